// Round 7
// baseline (4946.922 us; speedup 1.0000x reference)
//
#include <hip/hip_runtime.h>
#include <stdint.h>

typedef int i32x4 __attribute__((ext_vector_type(4)));

#define TWO_LOG2E 2.8853900817779268f

// ---------------- ws layout ----------------
// [0,8)            : thrbits[2] (uint, atomicMax of |w| bits)
// [4096, +16MB)    : Xq  [32768][512] int8
// then             : WriT [1024][512] int8  (n = dir*512 + j, k = i)
// then             : WrhT [2][512][512] int8 (row j, col i)
#define WS_XQ_OFF   4096
#define XQ_BYTES    ((size_t)32768 * 512)
#define WRIT_BYTES  ((size_t)1024 * 512)
#define WRHT_BYTES  ((size_t)2 * 512 * 512)

// Signed int8 dot4 via the BUILTIN only. Round 5 proved the raw
// "v_dot4_i32_i8" mnemonic assembles on gfx950 but computes different
// semantics than the builtin's lowering — never hand-pick the mnemonic.
static __device__ __forceinline__ int dot4(int a, int b, int c) {
#if __has_builtin(__builtin_amdgcn_sdot4)
    return __builtin_amdgcn_sdot4(a, b, c, false);
#else
    int r = c;
    r += (int)(signed char)(a) * (int)(signed char)(b);
    r += (int)(signed char)(a >> 8) * (int)(signed char)(b >> 8);
    r += (int)(signed char)(a >> 16) * (int)(signed char)(b >> 16);
    r += (int)(signed char)(a >> 24) * (int)(signed char)(b >> 24);
    return r;
#endif
}

// ---------------- threshold = max |w| over [w_ri; w_rh] per direction ----------------
__global__ __launch_bounds__(256) void k_absmax(const float* __restrict__ wri_f,
                                                const float* __restrict__ wrh_f,
                                                const float* __restrict__ wri_b,
                                                const float* __restrict__ wrh_b,
                                                unsigned* thrbits) {
    int dir = blockIdx.y;
    const float* a = dir ? wri_b : wri_f;
    const float* c = dir ? wrh_b : wrh_f;
    float m = 0.f;
    for (int i = blockIdx.x * 256 + threadIdx.x; i < 512 * 512; i += gridDim.x * 256) {
        m = fmaxf(m, fabsf(a[i]));
        m = fmaxf(m, fabsf(c[i]));
    }
    __shared__ float red[256];
    red[threadIdx.x] = m;
    __syncthreads();
    for (int s = 128; s > 0; s >>= 1) {
        if (threadIdx.x < s) red[threadIdx.x] = fmaxf(red[threadIdx.x], red[threadIdx.x + s]);
        __syncthreads();
    }
    if (threadIdx.x == 0) atomicMax(&thrbits[dir], __float_as_uint(red[0]));
}

// ---------------- quantize weights + transpose (WT[j][i] = round(W[i][j]/s)) ----------------
__global__ __launch_bounds__(256) void k_quant_w(const float* __restrict__ wri_f,
                                                 const float* __restrict__ wrh_f,
                                                 const float* __restrict__ wri_b,
                                                 const float* __restrict__ wrh_b,
                                                 const unsigned* __restrict__ thrbits,
                                                 signed char* __restrict__ writ,
                                                 signed char* __restrict__ wrht) {
    int id = blockIdx.x;             // 256 blocks
    int dir = id & 1;
    int which = (id >> 1) & 1;       // 0 = ri, 1 = rh
    int tile = id >> 2;              // 0..63  (8x8 tiles of 64x64)
    int ti = tile >> 3, tj = tile & 7;
    const float* src = which ? (dir ? wrh_b : wrh_f) : (dir ? wri_b : wri_f);
    signed char* dst = which ? (wrht + (size_t)dir * 512 * 512) : (writ + (size_t)dir * 512 * 512);
    float s = __uint_as_float(thrbits[dir]) / 127.0f;
    __shared__ signed char t8[64][68];
    int tx = threadIdx.x & 63, ty = threadIdx.x >> 6;
    int i0 = ti * 64, j0 = tj * 64;
#pragma unroll
    for (int r = 0; r < 16; ++r) {
        int il = r * 4 + ty;
        float w = src[(size_t)(i0 + il) * 512 + j0 + tx];
        float q = rintf(w / s);
        q = fminf(fmaxf(q, -127.f), 127.f);
        t8[il][tx] = (signed char)(int)q;
    }
    __syncthreads();
#pragma unroll
    for (int r = 0; r < 16; ++r) {
        int jl = r * 4 + ty;
        dst[(size_t)(j0 + jl) * 512 + i0 + tx] = t8[tx][jl];  // WT[j][i]
    }
}

// ---------------- quantize inputs: xq = round(clip(x,-1,1)*127) ----------------
__global__ __launch_bounds__(256) void k_quant_x(const float* __restrict__ x,
                                                 signed char* __restrict__ xq) {
    int i = blockIdx.x * 256 + threadIdx.x;   // one float4 per thread, 16384 blocks
    float4 v = ((const float4*)x)[i];
    int q0 = (int)rintf(fminf(fmaxf(v.x, -1.f), 1.f) * 127.f);
    int q1 = (int)rintf(fminf(fmaxf(v.y, -1.f), 1.f) * 127.f);
    int q2 = (int)rintf(fminf(fmaxf(v.z, -1.f), 1.f) * 127.f);
    int q3 = (int)rintf(fminf(fmaxf(v.w, -1.f), 1.f) * 127.f);
    ((int*)xq)[i] = (q0 & 255) | ((q1 & 255) << 8) | ((q2 & 255) << 16) | ((q3 & 255) << 24);
}

// ---------------- GEMM: out[t*16+b][n] = (Xq . WriT[n]) * gs2 + b[n]*2log2e ----------------
__global__ __launch_bounds__(256, 2) void k_gemm_xif(const signed char* __restrict__ xq,
                                                     const signed char* __restrict__ writ,
                                                     const float* __restrict__ b_f,
                                                     const float* __restrict__ b_b,
                                                     const unsigned* __restrict__ thrbits,
                                                     float* __restrict__ out) {
    int bid = blockIdx.x;        // 2048 = 256 Mtiles * 8 Ntiles
    int mt8 = bid >> 3;
    int nt8 = bid & 7;
    int w = threadIdx.x >> 6, lane = threadIdx.x & 63;
    int l15 = lane & 15, q = lane >> 4;
    int M0 = mt8 * 128 + (w >> 1) * 64;
    int N0 = nt8 * 128 + (w & 1) * 64;
    int dir = N0 >> 9;
    float thr = __uint_as_float(thrbits[dir]);
    float gs2 = thr * (TWO_LOG2E / (127.f * 127.f));
    const float* bp = dir ? b_b : b_f;
    float bi2[4];
#pragma unroll
    for (int nt = 0; nt < 4; ++nt)
        bi2[nt] = bp[(N0 & 511) + nt * 16 + l15] * TWO_LOG2E;

    i32x4 acc[4][4];
#pragma unroll
    for (int mt = 0; mt < 4; ++mt)
#pragma unroll
        for (int nt = 0; nt < 4; ++nt)
            acc[mt][nt] = (i32x4){0, 0, 0, 0};

#pragma unroll
    for (int kb = 0; kb < 8; ++kb) {
        i32x4 af[4], bf[4];
#pragma unroll
        for (int mt = 0; mt < 4; ++mt)
            af[mt] = *(const i32x4*)(xq + (size_t)(M0 + mt * 16 + l15) * 512 + kb * 64 + q * 16);
#pragma unroll
        for (int nt = 0; nt < 4; ++nt)
            bf[nt] = *(const i32x4*)(writ + (size_t)(N0 + nt * 16 + l15) * 512 + kb * 64 + q * 16);
#pragma unroll
        for (int mt = 0; mt < 4; ++mt)
#pragma unroll
            for (int nt = 0; nt < 4; ++nt)
                acc[mt][nt] = __builtin_amdgcn_mfma_i32_16x16x64_i8(af[mt], bf[nt], acc[mt][nt], 0, 0, 0);
    }
#pragma unroll
    for (int mt = 0; mt < 4; ++mt)
#pragma unroll
        for (int nt = 0; nt < 4; ++nt)
#pragma unroll
            for (int r = 0; r < 4; ++r) {
                int row = M0 + mt * 16 + q * 4 + r;
                int col = N0 + nt * 16 + l15;
                out[(size_t)row * 1024 + col] = fmaf((float)acc[mt][nt][r], gs2, bi2[nt]);
            }
}

// ---------------- persistent recurrence: 1 WG per (dir, batch), 32 WGs x 1024 thr ------------
// k-sliced dot4 GEMV. 1024 lanes = 128 col-groups (4 cols each) x 8 k-slices (64 B each).
// Per lane: 16 i32x4 weights (64 VGPRs), 4 x ds_read_b128 of its state slice per step
// (LDS broadcast return: 64 KB/step/CU vs 256 KB in the round-2 layout), 64 dot4,
// 3-round shfl_xor butterfly to assemble full sums. Two lanes share each column's
// epilogue (duplicate compute, split stores: s<4 -> float out, s>=4 -> state byte).
// Slices padded to 72 B so the 8 addresses/instr hit distinct banks.
// h127 = rint(127*tanh) = rint(127 - 254 / (1 + exp2(acc*gs2 + xi)))
__global__ __launch_bounds__(1024, 1) void k_rnn(const signed char* __restrict__ wrht,
                                                 const unsigned* __restrict__ thrbits,
                                                 float* __restrict__ out) {
    int bid = blockIdx.x;           // 32: dir*16 + batch
    int dir = bid >> 4, batch = bid & 15;
    int tid = threadIdx.x;
    int g = tid >> 3;               // col group 0..127, owns cols 4g..4g+3
    int s = tid & 7;                // k-slice 0..7 (64 B each)
    int cmy = 4 * g + (s & 3);      // this lane's epilogue column
    float thr = __uint_as_float(thrbits[dir]);
    float gs2 = thr * (TWO_LOG2E / (127.f * 127.f));
    const signed char* wq = wrht + (size_t)dir * 512 * 512;

    // weights: 4 cols x 64-B slice = 16 i32x4 = 64 VGPRs (static indexing only)
    i32x4 w[4][4];
#pragma unroll
    for (int i = 0; i < 4; ++i)
#pragma unroll
        for (int j = 0; j < 4; ++j)
            w[i][j] = *(const i32x4*)(wq + (size_t)(4 * g + i) * 512 + s * 64 + j * 16);

    __shared__ __align__(16) signed char st[2][8 * 72];   // [buf][slice-padded state]
    for (int i = tid; i < 2 * 8 * 72 / 4; i += 1024) ((int*)st)[i] = 0;
    __syncthreads();

    const signed char* rdp0 = &st[0][s * 72];
    const signed char* rdp1 = &st[1][s * 72];
    int woff = (cmy >> 6) * 72 + (cmy & 63);   // padded write offset of col cmy's byte

    int t0 = dir ? 2047 : 0;
    const long long rowstride = (long long)(dir ? -1 : 1) * 16 * 1024;
    float* prow = out + (size_t)t0 * 16 * 1024 + (size_t)batch * 1024 + (size_t)dir * 512 + cmy;

    float xi = *prow;
    int pp = 0;
    for (int step = 0; step < 2048; ++step) {
        float* pnext = prow + ((step + 1 < 2048) ? rowstride : 0);
        float xin = *pnext;                       // prefetch next XiF

        const signed char* sp = pp ? rdp1 : rdp0;
        int a0 = 0, a1 = 0, a2 = 0, a3 = 0;       // 4 independent chains (ILP)
#pragma unroll
        for (int j = 0; j < 4; ++j) {
            i32x4 s4 = *(const i32x4*)(sp + j * 16);
            a0 = dot4(w[0][j][0], s4[0], a0); a0 = dot4(w[0][j][1], s4[1], a0);
            a0 = dot4(w[0][j][2], s4[2], a0); a0 = dot4(w[0][j][3], s4[3], a0);
            a1 = dot4(w[1][j][0], s4[0], a1); a1 = dot4(w[1][j][1], s4[1], a1);
            a1 = dot4(w[1][j][2], s4[2], a1); a1 = dot4(w[1][j][3], s4[3], a1);
            a2 = dot4(w[2][j][0], s4[0], a2); a2 = dot4(w[2][j][1], s4[1], a2);
            a2 = dot4(w[2][j][2], s4[2], a2); a2 = dot4(w[2][j][3], s4[3], a2);
            a3 = dot4(w[3][j][0], s4[0], a3); a3 = dot4(w[3][j][1], s4[1], a3);
            a3 = dot4(w[3][j][2], s4[2], a3); a3 = dot4(w[3][j][3], s4[3], a3);
        }
        // butterfly over the 8 k-slices: all lanes end with full sums of their 4 cols
        a0 += __shfl_xor(a0, 1); a1 += __shfl_xor(a1, 1);
        a2 += __shfl_xor(a2, 1); a3 += __shfl_xor(a3, 1);
        a0 += __shfl_xor(a0, 2); a1 += __shfl_xor(a1, 2);
        a2 += __shfl_xor(a2, 2); a3 += __shfl_xor(a3, 2);
        a0 += __shfl_xor(a0, 4); a1 += __shfl_xor(a1, 4);
        a2 += __shfl_xor(a2, 4); a3 += __shfl_xor(a3, 4);
        // static select of this lane's column sum (i = s&3)
        int t01 = (s & 1) ? a1 : a0;
        int t23 = (s & 1) ? a3 : a2;
        int afin = (s & 2) ? t23 : t01;

        float arg = fmaf((float)afin, gs2, xi);
        float e = __builtin_amdgcn_exp2f(arg);
        float r = __builtin_amdgcn_rcpf(1.0f + e);
        float h127 = rintf(fmaf(r, -254.0f, 127.0f));
        if (s < 4) *prow = h127 * (1.0f / 127.0f);        // float out (one writer/col)
        else st[pp ^ 1][woff] = (signed char)(int)h127;   // state byte (one writer/col)

        xi = xin;
        prow = pnext;
        // LDS-only barrier: don't drain vmcnt (out stores / xi prefetch stay in flight)
        asm volatile("s_waitcnt lgkmcnt(0)" ::: "memory");
        __builtin_amdgcn_s_barrier();
        __builtin_amdgcn_sched_barrier(0);
        pp ^= 1;
    }
}

extern "C" void kernel_launch(void* const* d_in, const int* in_sizes, int n_in,
                              void* d_out, int out_size, void* d_ws, size_t ws_size,
                              hipStream_t stream) {
    const float* x     = (const float*)d_in[0];
    const float* wri_f = (const float*)d_in[1];
    const float* wrh_f = (const float*)d_in[2];
    const float* b_f   = (const float*)d_in[3];
    const float* wri_b = (const float*)d_in[4];
    const float* wrh_b = (const float*)d_in[5];
    const float* b_b   = (const float*)d_in[6];
    float* out = (float*)d_out;
    char* ws = (char*)d_ws;

    size_t need = WS_XQ_OFF + XQ_BYTES + WRIT_BYTES + WRHT_BYTES;
    if (ws_size < need) return;

    unsigned* thrbits = (unsigned*)ws;
    signed char* xq   = (signed char*)(ws + WS_XQ_OFF);
    signed char* writ = xq + XQ_BYTES;
    signed char* wrht = writ + WRIT_BYTES;

    hipMemsetAsync(thrbits, 0, 8, stream);
    k_absmax<<<dim3(64, 2), 256, 0, stream>>>(wri_f, wrh_f, wri_b, wrh_b, thrbits);
    k_quant_w<<<256, 256, 0, stream>>>(wri_f, wrh_f, wri_b, wrh_b, thrbits, writ, wrht);
    k_quant_x<<<16384, 256, 0, stream>>>(x, xq);
    k_gemm_xif<<<2048, 256, 0, stream>>>(xq, writ, b_f, b_b, thrbits, out);
    k_rnn<<<32, 1024, 0, stream>>>(wrht, thrbits, out);
}

// Round 9
// 2425.365 us; speedup vs baseline: 2.0397x; 2.0397x over previous
//
#include <hip/hip_runtime.h>
#include <stdint.h>

typedef int i32x4 __attribute__((ext_vector_type(4)));

#define TWO_LOG2E 2.8853900817779268f

// ---------------- ws layout ----------------
// [0,8)            : thrbits[2] (uint, atomicMax of |w| bits)
// [4096, +16MB)    : Xq  [32768][512] int8
// then             : WriT [1024][512] int8  (n = dir*512 + j, k = i)
// then             : WrhT [2][512][512] int8 (row j, col i)
#define WS_XQ_OFF   4096
#define XQ_BYTES    ((size_t)32768 * 512)
#define WRIT_BYTES  ((size_t)1024 * 512)
#define WRHT_BYTES  ((size_t)2 * 512 * 512)

// Signed int8 dot4 via the BUILTIN only (round 5: the raw mnemonic has
// different semantics; round 8: raw-asm MFMA corrupts registers without
// hand-inserted hazard NOPs — stick to builtins for compute).
static __device__ __forceinline__ int dot4(int a, int b, int c) {
#if __has_builtin(__builtin_amdgcn_sdot4)
    return __builtin_amdgcn_sdot4(a, b, c, false);
#else
    int r = c;
    r += (int)(signed char)(a) * (int)(signed char)(b);
    r += (int)(signed char)(a >> 8) * (int)(signed char)(b >> 8);
    r += (int)(signed char)(a >> 16) * (int)(signed char)(b >> 16);
    r += (int)(signed char)(a >> 24) * (int)(signed char)(b >> 24);
    return r;
#endif
}

// ---------------- threshold = max |w| over [w_ri; w_rh] per direction ----------------
__global__ __launch_bounds__(256) void k_absmax(const float* __restrict__ wri_f,
                                                const float* __restrict__ wrh_f,
                                                const float* __restrict__ wri_b,
                                                const float* __restrict__ wrh_b,
                                                unsigned* thrbits) {
    int dir = blockIdx.y;
    const float* a = dir ? wri_b : wri_f;
    const float* c = dir ? wrh_b : wrh_f;
    float m = 0.f;
    for (int i = blockIdx.x * 256 + threadIdx.x; i < 512 * 512; i += gridDim.x * 256) {
        m = fmaxf(m, fabsf(a[i]));
        m = fmaxf(m, fabsf(c[i]));
    }
    __shared__ float red[256];
    red[threadIdx.x] = m;
    __syncthreads();
    for (int s = 128; s > 0; s >>= 1) {
        if (threadIdx.x < s) red[threadIdx.x] = fmaxf(red[threadIdx.x], red[threadIdx.x + s]);
        __syncthreads();
    }
    if (threadIdx.x == 0) atomicMax(&thrbits[dir], __float_as_uint(red[0]));
}

// ---------------- quantize weights + transpose (WT[j][i] = round(W[i][j]/s)) ----------------
__global__ __launch_bounds__(256) void k_quant_w(const float* __restrict__ wri_f,
                                                 const float* __restrict__ wrh_f,
                                                 const float* __restrict__ wri_b,
                                                 const float* __restrict__ wrh_b,
                                                 const unsigned* __restrict__ thrbits,
                                                 signed char* __restrict__ writ,
                                                 signed char* __restrict__ wrht) {
    int id = blockIdx.x;             // 256 blocks
    int dir = id & 1;
    int which = (id >> 1) & 1;       // 0 = ri, 1 = rh
    int tile = id >> 2;              // 0..63  (8x8 tiles of 64x64)
    int ti = tile >> 3, tj = tile & 7;
    const float* src = which ? (dir ? wrh_b : wrh_f) : (dir ? wri_b : wri_f);
    signed char* dst = which ? (wrht + (size_t)dir * 512 * 512) : (writ + (size_t)dir * 512 * 512);
    float s = __uint_as_float(thrbits[dir]) / 127.0f;
    __shared__ signed char t8[64][68];
    int tx = threadIdx.x & 63, ty = threadIdx.x >> 6;
    int i0 = ti * 64, j0 = tj * 64;
#pragma unroll
    for (int r = 0; r < 16; ++r) {
        int il = r * 4 + ty;
        float w = src[(size_t)(i0 + il) * 512 + j0 + tx];
        float q = rintf(w / s);
        q = fminf(fmaxf(q, -127.f), 127.f);
        t8[il][tx] = (signed char)(int)q;
    }
    __syncthreads();
#pragma unroll
    for (int r = 0; r < 16; ++r) {
        int jl = r * 4 + ty;
        dst[(size_t)(j0 + jl) * 512 + i0 + tx] = t8[tx][jl];  // WT[j][i]
    }
}

// ---------------- quantize inputs: xq = round(clip(x,-1,1)*127) ----------------
__global__ __launch_bounds__(256) void k_quant_x(const float* __restrict__ x,
                                                 signed char* __restrict__ xq) {
    int i = blockIdx.x * 256 + threadIdx.x;   // one float4 per thread, 16384 blocks
    float4 v = ((const float4*)x)[i];
    int q0 = (int)rintf(fminf(fmaxf(v.x, -1.f), 1.f) * 127.f);
    int q1 = (int)rintf(fminf(fmaxf(v.y, -1.f), 1.f) * 127.f);
    int q2 = (int)rintf(fminf(fmaxf(v.z, -1.f), 1.f) * 127.f);
    int q3 = (int)rintf(fminf(fmaxf(v.w, -1.f), 1.f) * 127.f);
    ((int*)xq)[i] = (q0 & 255) | ((q1 & 255) << 8) | ((q2 & 255) << 16) | ((q3 & 255) << 24);
}

// ---------------- GEMM: out[t*16+b][n] = (Xq . WriT[n]) * gs2 + b[n]*2log2e ----------------
__global__ __launch_bounds__(256, 2) void k_gemm_xif(const signed char* __restrict__ xq,
                                                     const signed char* __restrict__ writ,
                                                     const float* __restrict__ b_f,
                                                     const float* __restrict__ b_b,
                                                     const unsigned* __restrict__ thrbits,
                                                     float* __restrict__ out) {
    int bid = blockIdx.x;        // 2048 = 256 Mtiles * 8 Ntiles
    int mt8 = bid >> 3;
    int nt8 = bid & 7;
    int w = threadIdx.x >> 6, lane = threadIdx.x & 63;
    int l15 = lane & 15, q = lane >> 4;
    int M0 = mt8 * 128 + (w >> 1) * 64;
    int N0 = nt8 * 128 + (w & 1) * 64;
    int dir = N0 >> 9;
    float thr = __uint_as_float(thrbits[dir]);
    float gs2 = thr * (TWO_LOG2E / (127.f * 127.f));
    const float* bp = dir ? b_b : b_f;
    float bi2[4];
#pragma unroll
    for (int nt = 0; nt < 4; ++nt)
        bi2[nt] = bp[(N0 & 511) + nt * 16 + l15] * TWO_LOG2E;

    i32x4 acc[4][4];
#pragma unroll
    for (int mt = 0; mt < 4; ++mt)
#pragma unroll
        for (int nt = 0; nt < 4; ++nt)
            acc[mt][nt] = (i32x4){0, 0, 0, 0};

#pragma unroll
    for (int kb = 0; kb < 8; ++kb) {
        i32x4 af[4], bf[4];
#pragma unroll
        for (int mt = 0; mt < 4; ++mt)
            af[mt] = *(const i32x4*)(xq + (size_t)(M0 + mt * 16 + l15) * 512 + kb * 64 + q * 16);
#pragma unroll
        for (int nt = 0; nt < 4; ++nt)
            bf[nt] = *(const i32x4*)(writ + (size_t)(N0 + nt * 16 + l15) * 512 + kb * 64 + q * 16);
#pragma unroll
        for (int mt = 0; mt < 4; ++mt)
#pragma unroll
            for (int nt = 0; nt < 4; ++nt)
                acc[mt][nt] = __builtin_amdgcn_mfma_i32_16x16x64_i8(af[mt], bf[nt], acc[mt][nt], 0, 0, 0);
    }
#pragma unroll
    for (int mt = 0; mt < 4; ++mt)
#pragma unroll
        for (int nt = 0; nt < 4; ++nt)
#pragma unroll
            for (int r = 0; r < 4; ++r) {
                int row = M0 + mt * 16 + q * 4 + r;
                int col = N0 + nt * 16 + l15;
                out[(size_t)row * 1024 + col] = fmaf((float)acc[mt][nt][r], gs2, bi2[nt]);
            }
}

// ---------------- persistent recurrence: 1 WG per (dir, batch), 32 WGs x 1024 thr ------------
// 2-way k-split dot4 GEMV. Lane = (col n = tid>>1, half h = tid&1). Per-lane weights:
// 256 B = 16 i32x4 = 64 VGPRs — small enough that the RA keeps them in arch VGPRs
// (r2/r6's 128-dword array was AGPR-homed -> ~512 cyc/SIMD of v_accvgpr_read per step).
// __launch_bounds__(1024,4) pins the 128-reg budget. Cross-lane: ONE shfl_xor(.,1)
// (DPP quad-perm) — r7's failure was 3 dependent butterfly rounds, not shuffling per se.
// Per instr each wave reads 2 distinct LDS addresses (2-way broadcast = free, m136).
// h127 = rint(127*tanh) = rint(127 - 254 / (1 + exp2(acc*gs2 + xi)))
__global__ __launch_bounds__(1024, 4) void k_rnn(const signed char* __restrict__ wrht,
                                                 const unsigned* __restrict__ thrbits,
                                                 float* __restrict__ out) {
    int bid = blockIdx.x;           // 32: dir*16 + batch
    int dir = bid >> 4, batch = bid & 15;
    int tid = threadIdx.x;
    int n = tid >> 1;               // this lane's output column
    int h = tid & 1;                // k-half (256 B)
    float thr = __uint_as_float(thrbits[dir]);
    float gs2 = thr * (TWO_LOG2E / (127.f * 127.f));
    const signed char* wq = wrht + (size_t)dir * 512 * 512 + (size_t)n * 512 + h * 256;

    // half W row resident in 64 arch VGPRs: 16 x i32x4, static indexing only
    i32x4 w[16];
#pragma unroll
    for (int i = 0; i < 16; ++i)
        w[i] = *(const i32x4*)(wq + i * 16);

    __shared__ __align__(16) signed char st[2][512];
    if (tid < 256) ((int*)st)[tid] = 0;
    __syncthreads();

    int t0 = dir ? 2047 : 0;
    const long long rowstride = (long long)(dir ? -1 : 1) * 16 * 1024;
    float* prow = out + (size_t)t0 * 16 * 1024 + (size_t)batch * 1024 + (size_t)dir * 512 + n;

    float xi = *prow;
    int pp = 0;
    for (int step = 0; step < 2048; ++step) {
        // prefetch next step's XiF (hides HBM/L2 latency under the dot4 stream)
        float* pnext = prow + ((step + 1 < 2048) ? rowstride : 0);
        float xin = *pnext;

        const signed char* sp = &st[pp][h * 256];
        int a0 = 0, a1 = 0, a2 = 0, a3 = 0;     // 4 independent chains (ILP)
#pragma unroll
        for (int j = 0; j < 16; ++j) {
            i32x4 s4 = *(const i32x4*)(sp + j * 16);
            a0 = dot4(w[j][0], s4[0], a0);
            a1 = dot4(w[j][1], s4[1], a1);
            a2 = dot4(w[j][2], s4[2], a2);
            a3 = dot4(w[j][3], s4[3], a3);
        }
        int acc = (a0 + a1) + (a2 + a3);
        acc += __shfl_xor(acc, 1);              // combine the two k-halves

        float arg = fmaf((float)acc, gs2, xi);
        float e = __builtin_amdgcn_exp2f(arg);
        float r = __builtin_amdgcn_rcpf(1.0f + e);
        float h127 = rintf(fmaf(r, -254.0f, 127.0f));
        if (h == 0) *prow = h127 * (1.0f / 127.0f);       // float out (one writer/col)
        else st[pp ^ 1][n] = (signed char)(int)h127;      // state byte (one writer/col)

        xi = xin;
        prow = pnext;
        // LDS-only barrier: don't drain vmcnt (the h-store can stay in flight)
        asm volatile("s_waitcnt lgkmcnt(0)" ::: "memory");
        __builtin_amdgcn_s_barrier();
        __builtin_amdgcn_sched_barrier(0);
        pp ^= 1;
    }
}

extern "C" void kernel_launch(void* const* d_in, const int* in_sizes, int n_in,
                              void* d_out, int out_size, void* d_ws, size_t ws_size,
                              hipStream_t stream) {
    const float* x     = (const float*)d_in[0];
    const float* wri_f = (const float*)d_in[1];
    const float* wrh_f = (const float*)d_in[2];
    const float* b_f   = (const float*)d_in[3];
    const float* wri_b = (const float*)d_in[4];
    const float* wrh_b = (const float*)d_in[5];
    const float* b_b   = (const float*)d_in[6];
    float* out = (float*)d_out;
    char* ws = (char*)d_ws;

    size_t need = WS_XQ_OFF + XQ_BYTES + WRIT_BYTES + WRHT_BYTES;
    if (ws_size < need) return;

    unsigned* thrbits = (unsigned*)ws;
    signed char* xq   = (signed char*)(ws + WS_XQ_OFF);
    signed char* writ = xq + XQ_BYTES;
    signed char* wrht = writ + WRIT_BYTES;

    hipMemsetAsync(thrbits, 0, 8, stream);
    k_absmax<<<dim3(64, 2), 256, 0, stream>>>(wri_f, wrh_f, wri_b, wrh_b, thrbits);
    k_quant_w<<<256, 256, 0, stream>>>(wri_f, wrh_f, wri_b, wrh_b, thrbits, writ, wrht);
    k_quant_x<<<16384, 256, 0, stream>>>(x, xq);
    k_gemm_xif<<<2048, 256, 0, stream>>>(xq, writ, b_f, b_b, thrbits, out);
    k_rnn<<<32, 1024, 0, stream>>>(wrht, thrbits, out);
}

// Round 10
// 1850.096 us; speedup vs baseline: 2.6739x; 1.3109x over previous
//
#include <hip/hip_runtime.h>
#include <stdint.h>

typedef int i32x4 __attribute__((ext_vector_type(4)));

#define TWO_LOG2E 2.8853900817779268f

// ---------------- ws layout ----------------
// [0,8)            : thrbits[2] (uint, atomicMax of |w| bits)
// [4096, +16MB)    : Xq  [32768][512] int8
// then             : WriT [1024][512] int8  (n = dir*512 + j, k = i)
// then             : WrhT [2][512][512] int8 (row j, col i)
#define WS_XQ_OFF   4096
#define XQ_BYTES    ((size_t)32768 * 512)
#define WRIT_BYTES  ((size_t)1024 * 512)
#define WRHT_BYTES  ((size_t)2 * 512 * 512)

// Signed int8 dot4 via the BUILTIN only (r5: raw "v_dot4_i32_i8" assembles but
// has different semantics; r8: raw-asm MFMA corrupts regs without hazard nops).
static __device__ __forceinline__ int dot4(int a, int b, int c) {
#if __has_builtin(__builtin_amdgcn_sdot4)
    return __builtin_amdgcn_sdot4(a, b, c, false);
#else
    int r = c;
    r += (int)(signed char)(a) * (int)(signed char)(b);
    r += (int)(signed char)(a >> 8) * (int)(signed char)(b >> 8);
    r += (int)(signed char)(a >> 16) * (int)(signed char)(b >> 16);
    r += (int)(signed char)(a >> 24) * (int)(signed char)(b >> 24);
    return r;
#endif
}

// ---------------- threshold = max |w| over [w_ri; w_rh] per direction ----------------
__global__ __launch_bounds__(256) void k_absmax(const float* __restrict__ wri_f,
                                                const float* __restrict__ wrh_f,
                                                const float* __restrict__ wri_b,
                                                const float* __restrict__ wrh_b,
                                                unsigned* thrbits) {
    int dir = blockIdx.y;
    const float* a = dir ? wri_b : wri_f;
    const float* c = dir ? wrh_b : wrh_f;
    float m = 0.f;
    for (int i = blockIdx.x * 256 + threadIdx.x; i < 512 * 512; i += gridDim.x * 256) {
        m = fmaxf(m, fabsf(a[i]));
        m = fmaxf(m, fabsf(c[i]));
    }
    __shared__ float red[256];
    red[threadIdx.x] = m;
    __syncthreads();
    for (int s = 128; s > 0; s >>= 1) {
        if (threadIdx.x < s) red[threadIdx.x] = fmaxf(red[threadIdx.x], red[threadIdx.x + s]);
        __syncthreads();
    }
    if (threadIdx.x == 0) atomicMax(&thrbits[dir], __float_as_uint(red[0]));
}

// ---------------- quantize weights + transpose (WT[j][i] = round(W[i][j]/s)) ----------------
__global__ __launch_bounds__(256) void k_quant_w(const float* __restrict__ wri_f,
                                                 const float* __restrict__ wrh_f,
                                                 const float* __restrict__ wri_b,
                                                 const float* __restrict__ wrh_b,
                                                 const unsigned* __restrict__ thrbits,
                                                 signed char* __restrict__ writ,
                                                 signed char* __restrict__ wrht) {
    int id = blockIdx.x;             // 256 blocks
    int dir = id & 1;
    int which = (id >> 1) & 1;       // 0 = ri, 1 = rh
    int tile = id >> 2;              // 0..63  (8x8 tiles of 64x64)
    int ti = tile >> 3, tj = tile & 7;
    const float* src = which ? (dir ? wrh_b : wrh_f) : (dir ? wri_b : wri_f);
    signed char* dst = which ? (wrht + (size_t)dir * 512 * 512) : (writ + (size_t)dir * 512 * 512);
    float s = __uint_as_float(thrbits[dir]) / 127.0f;
    __shared__ signed char t8[64][68];
    int tx = threadIdx.x & 63, ty = threadIdx.x >> 6;
    int i0 = ti * 64, j0 = tj * 64;
#pragma unroll
    for (int r = 0; r < 16; ++r) {
        int il = r * 4 + ty;
        float w = src[(size_t)(i0 + il) * 512 + j0 + tx];
        float q = rintf(w / s);
        q = fminf(fmaxf(q, -127.f), 127.f);
        t8[il][tx] = (signed char)(int)q;
    }
    __syncthreads();
#pragma unroll
    for (int r = 0; r < 16; ++r) {
        int jl = r * 4 + ty;
        dst[(size_t)(j0 + jl) * 512 + i0 + tx] = t8[tx][jl];  // WT[j][i]
    }
}

// ---------------- quantize inputs: xq = round(clip(x,-1,1)*127) ----------------
__global__ __launch_bounds__(256) void k_quant_x(const float* __restrict__ x,
                                                 signed char* __restrict__ xq) {
    int i = blockIdx.x * 256 + threadIdx.x;   // one float4 per thread, 16384 blocks
    float4 v = ((const float4*)x)[i];
    int q0 = (int)rintf(fminf(fmaxf(v.x, -1.f), 1.f) * 127.f);
    int q1 = (int)rintf(fminf(fmaxf(v.y, -1.f), 1.f) * 127.f);
    int q2 = (int)rintf(fminf(fmaxf(v.z, -1.f), 1.f) * 127.f);
    int q3 = (int)rintf(fminf(fmaxf(v.w, -1.f), 1.f) * 127.f);
    ((int*)xq)[i] = (q0 & 255) | ((q1 & 255) << 8) | ((q2 & 255) << 16) | ((q3 & 255) << 24);
}

// ---------------- GEMM: out[t*16+b][n] = (Xq . WriT[n]) * gs2 + b[n]*2log2e ----------------
__global__ __launch_bounds__(256, 2) void k_gemm_xif(const signed char* __restrict__ xq,
                                                     const signed char* __restrict__ writ,
                                                     const float* __restrict__ b_f,
                                                     const float* __restrict__ b_b,
                                                     const unsigned* __restrict__ thrbits,
                                                     float* __restrict__ out) {
    int bid = blockIdx.x;        // 2048 = 256 Mtiles * 8 Ntiles
    int mt8 = bid >> 3;
    int nt8 = bid & 7;
    int w = threadIdx.x >> 6, lane = threadIdx.x & 63;
    int l15 = lane & 15, q = lane >> 4;
    int M0 = mt8 * 128 + (w >> 1) * 64;
    int N0 = nt8 * 128 + (w & 1) * 64;
    int dir = N0 >> 9;
    float thr = __uint_as_float(thrbits[dir]);
    float gs2 = thr * (TWO_LOG2E / (127.f * 127.f));
    const float* bp = dir ? b_b : b_f;
    float bi2[4];
#pragma unroll
    for (int nt = 0; nt < 4; ++nt)
        bi2[nt] = bp[(N0 & 511) + nt * 16 + l15] * TWO_LOG2E;

    i32x4 acc[4][4];
#pragma unroll
    for (int mt = 0; mt < 4; ++mt)
#pragma unroll
        for (int nt = 0; nt < 4; ++nt)
            acc[mt][nt] = (i32x4){0, 0, 0, 0};

#pragma unroll
    for (int kb = 0; kb < 8; ++kb) {
        i32x4 af[4], bf[4];
#pragma unroll
        for (int mt = 0; mt < 4; ++mt)
            af[mt] = *(const i32x4*)(xq + (size_t)(M0 + mt * 16 + l15) * 512 + kb * 64 + q * 16);
#pragma unroll
        for (int nt = 0; nt < 4; ++nt)
            bf[nt] = *(const i32x4*)(writ + (size_t)(N0 + nt * 16 + l15) * 512 + kb * 64 + q * 16);
#pragma unroll
        for (int mt = 0; mt < 4; ++mt)
#pragma unroll
            for (int nt = 0; nt < 4; ++nt)
                acc[mt][nt] = __builtin_amdgcn_mfma_i32_16x16x64_i8(af[mt], bf[nt], acc[mt][nt], 0, 0, 0);
    }
#pragma unroll
    for (int mt = 0; mt < 4; ++mt)
#pragma unroll
        for (int nt = 0; nt < 4; ++nt)
#pragma unroll
            for (int r = 0; r < 4; ++r) {
                int row = M0 + mt * 16 + q * 4 + r;
                int col = N0 + nt * 16 + l15;
                out[(size_t)row * 1024 + col] = fmaf((float)acc[mt][nt][r], gs2, bi2[nt]);
            }
}

// ---------------- persistent recurrence: 1 WG per (dir, batch), 32 WGs x 1024 thr ------------
// k2-split dot4 GEMV with SKEWED halves. Lane = (col n = tid>>1, half h = tid&1).
// State halves at byte offsets 0 and 272 (16-B skew): per read instr j, h=0 hits
// bank quad {4j..4j+3}, h=1 hits {4j+4..4j+7} — disjoint -> conflict-free (r9's
// +256 layout aliased the same quad: 6.7e7 conflicts = +1024 cyc/step).
// Per-lane LDS traffic: 256 B/step (vs 512 in r2) -> LDS return ~512 cyc/step/CU.
// One shfl_xor(acc,1) combines the halves (r7 died on 3 DEPENDENT rounds, not 1).
// h127 = rint(127 - 254/(1+exp2(acc*gs2 + xi))) via magic-add RNE (validated r3/r4).
__global__ __launch_bounds__(1024, 2) void k_rnn(const signed char* __restrict__ wrht,
                                                 const unsigned* __restrict__ thrbits,
                                                 float* __restrict__ out) {
    int bid = blockIdx.x;           // 32: dir*16 + batch
    int dir = bid >> 4, batch = bid & 15;
    int tid = threadIdx.x;
    int n = tid >> 1;               // this lane's output column
    int h = tid & 1;                // k-half (256 B)
    float thr = __uint_as_float(thrbits[dir]);
    float gs2 = thr * (TWO_LOG2E / (127.f * 127.f));
    const signed char* wq = wrht + (size_t)dir * 512 * 512 + (size_t)n * 512 + h * 256;

    // half W row: 16 x i32x4 (64 VGPRs), static indexing only
    i32x4 w[16];
#pragma unroll
    for (int i = 0; i < 16; ++i)
        w[i] = *(const i32x4*)(wq + i * 16);

    __shared__ __align__(16) signed char st[2][544];  // halves at +0 and +272 (16-B skew)
    if (tid < 272) ((int*)st)[tid] = 0;
    __syncthreads();

    const signed char* rdp0 = &st[0][h * 272];
    const signed char* rdp1 = &st[1][h * 272];
    int woff = n + ((n >> 8) << 4);               // skewed write offset of col n's byte

    int t0 = dir ? 2047 : 0;
    const long long rowstride = (long long)(dir ? -1 : 1) * 16 * 1024;
    float* prow = out + (size_t)t0 * 16 * 1024 + (size_t)batch * 1024 + (size_t)dir * 512 + n;

    float xi = *prow;
    int pp = 0;
    for (int step = 0; step < 2048; ++step) {
        // prefetch next step's XiF (hides HBM/L2 latency under the dot4 stream)
        float* pnext = prow + ((step + 1 < 2048) ? rowstride : 0);
        float xin = *pnext;

        const signed char* sp = pp ? rdp1 : rdp0;
        int a0 = 0, a1 = 0, a2 = 0, a3 = 0;       // 4 independent chains (ILP)
#pragma unroll
        for (int j = 0; j < 16; ++j) {
            i32x4 s4 = *(const i32x4*)(sp + j * 16);
            a0 = dot4(w[j][0], s4[0], a0);
            a1 = dot4(w[j][1], s4[1], a1);
            a2 = dot4(w[j][2], s4[2], a2);
            a3 = dot4(w[j][3], s4[3], a3);
        }
        int acc = (a0 + a1) + (a2 + a3);
        acc += __shfl_xor(acc, 1);                // combine the two k-halves (DPP)

        float arg = fmaf((float)acc, gs2, xi);
        float e = __builtin_amdgcn_exp2f(arg);
        float rc = __builtin_amdgcn_rcpf(1.0f + e);
        float t = fmaf(rc, -254.0f, 127.0f);
        float mm = t + 12582912.0f;               // RNE round, |t| <= 127
        if (h == 0) *prow = (mm - 12582912.0f) * (1.0f / 127.0f);          // float out
        else st[pp ^ 1][woff] = (signed char)(__float_as_uint(mm) & 0xFFu); // state byte

        xi = xin;
        prow = pnext;
        // LDS-only barrier: don't drain vmcnt (the h-store can stay in flight)
        asm volatile("s_waitcnt lgkmcnt(0)" ::: "memory");
        __builtin_amdgcn_s_barrier();
        __builtin_amdgcn_sched_barrier(0);
        pp ^= 1;
    }
}

extern "C" void kernel_launch(void* const* d_in, const int* in_sizes, int n_in,
                              void* d_out, int out_size, void* d_ws, size_t ws_size,
                              hipStream_t stream) {
    const float* x     = (const float*)d_in[0];
    const float* wri_f = (const float*)d_in[1];
    const float* wrh_f = (const float*)d_in[2];
    const float* b_f   = (const float*)d_in[3];
    const float* wri_b = (const float*)d_in[4];
    const float* wrh_b = (const float*)d_in[5];
    const float* b_b   = (const float*)d_in[6];
    float* out = (float*)d_out;
    char* ws = (char*)d_ws;

    size_t need = WS_XQ_OFF + XQ_BYTES + WRIT_BYTES + WRHT_BYTES;
    if (ws_size < need) return;

    unsigned* thrbits = (unsigned*)ws;
    signed char* xq   = (signed char*)(ws + WS_XQ_OFF);
    signed char* writ = xq + XQ_BYTES;
    signed char* wrht = writ + WRIT_BYTES;

    hipMemsetAsync(thrbits, 0, 8, stream);
    k_absmax<<<dim3(64, 2), 256, 0, stream>>>(wri_f, wrh_f, wri_b, wrh_b, thrbits);
    k_quant_w<<<256, 256, 0, stream>>>(wri_f, wrh_f, wri_b, wrh_b, thrbits, writ, wrht);
    k_quant_x<<<16384, 256, 0, stream>>>(x, xq);
    k_gemm_xif<<<2048, 256, 0, stream>>>(xq, writ, b_f, b_b, thrbits, out);
    k_rnn<<<32, 1024, 0, stream>>>(wrht, thrbits, out);
}